// Round 10
// baseline (339.905 us; speedup 1.0000x reference)
//
#include <hip/hip_runtime.h>
#include <hip/hip_bf16.h>

// Problem: B=16, C=512, H=W=64 -> HW=4096, fp32.
// attn[b,c,d] = sum_n q[b,c,n]*kv[b,d,n]; P = softmax_d(attn);
// info[b,c,n] = sum_d P[b,c,d]*kv[b,d,n]; out = gamma*info + img.
//
// R10 structure:
//   prep_kv: txt f32 -> kv16 bf16 (in d_out) + kvT bf16 (in ws)
//   gemm_qk: attn partials = img(f32) * kv16^T; dbuf LDS, single barrier
//            per k-step, 1-deep early-issue (R7-proven), SPLITK=2
//   softmax: partial-sum + row softmax -> P bf16 (ws)
//   gemm_pv: out = gamma*(kvT * P^T) + img; NO-LDS, NO-BARRIER: fragments
//            loaded straight from global (L2-resident kvT/P — m169 lesson:
//            don't stage what L2 fits), fully-unrolled K, compiler pipelines.

constexpr int NB = 16;
constexpr int NC = 512;
constexpr int NHW = 4096;
constexpr int QKSPLIT = 2;

typedef float f32x4 __attribute__((ext_vector_type(4)));
typedef __bf16 bf16x4 __attribute__((ext_vector_type(4)));
typedef __bf16 bf16x8 __attribute__((ext_vector_type(8)));

__device__ __forceinline__ void gload16(const void* g, void* l) {
  __builtin_amdgcn_global_load_lds(
      (const __attribute__((address_space(1))) void*)g,
      (__attribute__((address_space(3))) void*)l, 16, 0, 0);
}

// ---------------------------------------------------------------------------
// gemm_qk: D[m][n'] = sum_k A[m][k]*B[n'][k], A f32 (img), B bf16 (kv16).
// Tile 128x128, BK=64, 8 waves (2Mx4N), wave tile 64x32.
// Double-buffered, ONE barrier per k-step (R7-proven).
// ---------------------------------------------------------------------------
template <int SPLITS>
__global__ __launch_bounds__(512) void gemm_qk(const float* __restrict__ Af,
                                               const __bf16* __restrict__ B,
                                               float* __restrict__ Dp) {
  __shared__ __bf16 sA[2][128 * 64];
  __shared__ __bf16 sB[2][128 * 64];

  const int t = threadIdx.x;
  const int lane = t & 63;
  const int wave = t >> 6;
  const int wr = wave >> 2;
  const int wc = wave & 3;

  // XCD-aware remap (NWG % 8 == 0)
  constexpr int NWG = 16 * NB * SPLITS;
  constexpr int QX = NWG / 8;
  int flat = blockIdx.x + 4 * (blockIdx.y + 4 * blockIdx.z);
  flat = (flat & 7) * QX + (flat >> 3);
  const int bx = flat & 3;
  const int by = (flat >> 2) & 3;
  const int bz = flat >> 4;
  const int batch = bz / SPLITS;
  const int split = bz % SPLITS;

  const int aRow0 = bx * 128;
  const int bRow0 = by * 128;
  constexpr int KSUB = NHW / SPLITS;
  constexpr int NT = KSUB / 64;
  const int kBeg = split * KSUB;

  // B staging (gload_lds): rows wave*16 + i*8 + (lane>>3), src chunk XOR
  const int rl = lane >> 3;
  const int csrc = ((lane & 7) ^ rl) * 8;
  const __bf16* Bbase = B + (long)batch * NC * NHW +
                        (long)(bRow0 + wave * 16 + rl) * NHW + csrc + kBeg;
  const int ldsOff = wave * 16 * 64;

  // A staging (f32 regs): k-cols c4..c4+3, rows rb + 32*i
  const int c4 = (t & 15) * 4;
  const int rb = t >> 4;
  const float* Abase =
      Af + (long)batch * NC * NHW + (long)(aRow0 + rb) * NHW + kBeg + c4;

  f32x4 ra[4];
  auto loadA = [&](int kof) {
#pragma unroll
    for (int i = 0; i < 4; ++i)
      ra[i] = *(const f32x4*)(Abase + kof + (long)(32 * i) * NHW);
  };
  auto writeA = [&](int buf) {
#pragma unroll
    for (int i = 0; i < 4; ++i) {
      const int r = rb + 32 * i;
      const int idx = r * 64 + (c4 ^ ((r & 7) << 3));
      bf16x4 h = {(__bf16)ra[i].x, (__bf16)ra[i].y, (__bf16)ra[i].z,
                  (__bf16)ra[i].w};
      *(bf16x4*)&sA[buf][idx] = h;
    }
  };
  auto stageB = [&](int buf, int kof) {
#pragma unroll
    for (int i = 0; i < 2; ++i)
      gload16(Bbase + kof + (long)(i * 8) * NHW, &sB[buf][ldsOff + i * 8 * 64]);
  };

  f32x4 acc[4][2] = {};
  auto compute_tile = [&](int buf) {
#pragma unroll
    for (int kk = 0; kk < 2; ++kk) {
      const int kb = kk * 32 + ((lane >> 4) << 3);
      bf16x8 af[4], bfr[2];
#pragma unroll
      for (int m = 0; m < 4; ++m) {
        const int r = wr * 64 + m * 16 + (lane & 15);
        af[m] = *(const bf16x8*)&sA[buf][r * 64 + (kb ^ ((r & 7) << 3))];
      }
#pragma unroll
      for (int n = 0; n < 2; ++n) {
        const int r = wc * 32 + n * 16 + (lane & 15);
        bfr[n] = *(const bf16x8*)&sB[buf][r * 64 + (kb ^ ((r & 7) << 3))];
      }
#pragma unroll
      for (int m = 0; m < 4; ++m)
#pragma unroll
        for (int n = 0; n < 2; ++n)
          acc[m][n] = __builtin_amdgcn_mfma_f32_16x16x32_bf16(
              af[m], bfr[n], acc[m][n], 0, 0, 0);
    }
  };

  // prologue: fully stage tile 0 (A loads first, then B gloads)
  loadA(0);      // 4 vmem
  stageB(0, 0);  // 2 vmem
  asm volatile("s_waitcnt vmcnt(2)" ::: "memory");  // A(0) landed
  writeA(0);
  asm volatile("s_waitcnt vmcnt(0) lgkmcnt(0)" ::: "memory");  // B(0) + ds
  __builtin_amdgcn_s_barrier();

  int cur = 0;
#pragma unroll 1
  for (int tt = 0; tt < NT; ++tt) {
    const bool more = (tt + 1) < NT;
    if (more) {
      loadA((tt + 1) * 64);            // 4 vmem -> regs
      stageB(cur ^ 1, (tt + 1) * 64);  // 2 vmem -> other LDS buffer
      asm volatile("" ::: "memory");   // pin issue point before compute
    }
    compute_tile(cur);  // reads buf cur only
    if (more) {
      asm volatile("s_waitcnt vmcnt(2)" ::: "memory");  // A(t+1) landed
      writeA(cur ^ 1);
      asm volatile("s_waitcnt vmcnt(0) lgkmcnt(0)" ::: "memory");  // B + ds
      __builtin_amdgcn_s_barrier();  // single barrier: buf cur^1 ready
      cur ^= 1;
    }
  }

  // epilogue: partial store. C/D layout: col=lane&15, row=(lane>>4)*4+reg
  float* D = Dp + ((long)split * NB + batch) * NC * NC;
  const int m0 = aRow0 + wr * 64;
  const int n0 = bRow0 + wc * 32;
#pragma unroll
  for (int m = 0; m < 4; ++m)
#pragma unroll
    for (int n = 0; n < 2; ++n) {
      const int row0 = m0 + m * 16 + ((lane >> 4) << 2);
      const int col = n0 + n * 16 + (lane & 15);
#pragma unroll
      for (int r = 0; r < 4; ++r)
        D[(long)(row0 + r) * NC + col] = acc[m][n][r];
    }
}

// ---------------------------------------------------------------------------
// gemm_pv: out[b][c][sp] = gamma * sum_d kvT[sp][d]*P[c][d] + img[b][c][sp].
// NO LDS / NO BARRIERS. Each lane loads its MFMA fragments directly from
// global (bf16x8 = 16B; 16-lane groups form 64B segments). kvT (4MB/batch)
// and P (0.5MB/batch) are L2-resident under the XCD-batch-local swizzle, so
// staging them in LDS only added barriers (m169 lesson). Fully unrolled
// K=512 -> compiler software-pipelines the 96 loads freely.
// Block: 256 thr = 4 waves (2sp x 2ch); tile 64sp x 128ch; wave 32x64.
// ---------------------------------------------------------------------------
__global__ __launch_bounds__(256) void gemm_pv(const __bf16* __restrict__ A,
                                               const __bf16* __restrict__ B,
                                               const float* __restrict__ img,
                                               const float* __restrict__ gammap,
                                               float* __restrict__ outp) {
  const int t = threadIdx.x;  // 0..255
  const int lane = t & 63;
  const int wave = t >> 6;    // 0..3
  const int wsp = wave >> 1;  // 0..1 (spatial half)
  const int wch = wave & 1;   // 0..1 (channel half)

  constexpr int GX = NHW / 64;      // 64
  constexpr int NWG = GX * 4 * NB;  // 4096
  constexpr int QX = NWG / 8;       // 512
  int flat = blockIdx.x + GX * (blockIdx.y + 4 * blockIdx.z);
  flat = (flat & 7) * QX + (flat >> 3);
  const int bx = flat & 63;
  const int by = (flat >> 6) & 3;
  const int batch = flat >> 8;

  const int aRow0 = bx * 64;   // spatial
  const int bRow0 = by * 128;  // channel

  const int rl = lane & 15;        // fragment row within 16
  const int kl = (lane >> 4) * 8;  // fragment k offset (8 bf16 = 16B)

  // per-fragment global base pointers (K strides into offset immediates)
  const __bf16* Ab0 =
      A + (long)batch * NHW * NC + (long)(aRow0 + wsp * 32 + rl) * NC + kl;
  const __bf16* Ab1 = Ab0 + 16 * NC;
  const __bf16* Bb0 =
      B + (long)batch * NC * NC + (long)(bRow0 + wch * 64 + rl) * NC + kl;
  const __bf16* Bb1 = Bb0 + 16 * NC;
  const __bf16* Bb2 = Bb0 + 32 * NC;
  const __bf16* Bb3 = Bb0 + 48 * NC;

  f32x4 acc[2][4] = {};

#pragma unroll
  for (int ks = 0; ks < 16; ++ks) {  // K = 16 x 32
    const int ko = ks * 32;
    bf16x8 a0 = *(const bf16x8*)(Ab0 + ko);
    bf16x8 a1 = *(const bf16x8*)(Ab1 + ko);
    bf16x8 b0 = *(const bf16x8*)(Bb0 + ko);
    bf16x8 b1 = *(const bf16x8*)(Bb1 + ko);
    bf16x8 b2 = *(const bf16x8*)(Bb2 + ko);
    bf16x8 b3 = *(const bf16x8*)(Bb3 + ko);
    acc[0][0] = __builtin_amdgcn_mfma_f32_16x16x32_bf16(a0, b0, acc[0][0], 0, 0, 0);
    acc[0][1] = __builtin_amdgcn_mfma_f32_16x16x32_bf16(a0, b1, acc[0][1], 0, 0, 0);
    acc[0][2] = __builtin_amdgcn_mfma_f32_16x16x32_bf16(a0, b2, acc[0][2], 0, 0, 0);
    acc[0][3] = __builtin_amdgcn_mfma_f32_16x16x32_bf16(a0, b3, acc[0][3], 0, 0, 0);
    acc[1][0] = __builtin_amdgcn_mfma_f32_16x16x32_bf16(a1, b0, acc[1][0], 0, 0, 0);
    acc[1][1] = __builtin_amdgcn_mfma_f32_16x16x32_bf16(a1, b1, acc[1][1], 0, 0, 0);
    acc[1][2] = __builtin_amdgcn_mfma_f32_16x16x32_bf16(a1, b2, acc[1][2], 0, 0, 0);
    acc[1][3] = __builtin_amdgcn_mfma_f32_16x16x32_bf16(a1, b3, acc[1][3], 0, 0, 0);
  }

  // epilogue: out[b][ch][sp] = gamma*acc + img
  const float g = gammap[0];
  const long obase = (long)batch * NC * NHW;
  const int sp0 = aRow0 + wsp * 32;
  const int ch0 = bRow0 + wch * 64;
#pragma unroll
  for (int m = 0; m < 2; ++m)
#pragma unroll
    for (int n = 0; n < 4; ++n) {
      const int sp = sp0 + m * 16 + ((lane >> 4) << 2);
      const int ch = ch0 + n * 16 + (lane & 15);
      const long idx = obase + (long)ch * NHW + sp;
      f32x4 iv = *(const f32x4*)(img + idx);
      f32x4 ov;
#pragma unroll
      for (int r = 0; r < 4; ++r) ov[r] = g * acc[m][n][r] + iv[r];
      *(f32x4*)(outp + idx) = ov;
    }
}

// ---------------------------------------------------------------------------
// prep_kv: kv[b][d][n] f32 -> kv16[b][d][n] bf16 AND kvT[b][n][d] bf16.
// ---------------------------------------------------------------------------
__global__ __launch_bounds__(256) void prep_kv(const float* __restrict__ kv,
                                               __bf16* __restrict__ kv16,
                                               __bf16* __restrict__ kvT) {
  __shared__ __bf16 tile[64 * 68];
  const int t = threadIdx.x;
  const int n0 = blockIdx.x * 64;
  const int d0 = blockIdx.y * 64;
  const long ibase = (long)blockIdx.z * NC * NHW;

  const int nc4 = (t & 15) * 4;
  const int dr0 = t >> 4;
#pragma unroll
  for (int i = 0; i < 4; ++i) {
    const int dr = dr0 + 16 * i;
    f32x4 v = *(const f32x4*)(kv + ibase + (long)(d0 + dr) * NHW + n0 + nc4);
    bf16x4 h = {(__bf16)v.x, (__bf16)v.y, (__bf16)v.z, (__bf16)v.w};
    *(bf16x4*)&tile[dr * 68 + nc4] = h;
    *(bf16x4*)(kv16 + ibase + (long)(d0 + dr) * NHW + n0 + nc4) = h;
  }
  __syncthreads();

  const long obase = (long)blockIdx.z * NHW * NC;
  const int nr = t >> 2;
  const int dc0 = t & 3;
#pragma unroll
  for (int i = 0; i < 2; ++i) {
    const int dc = dc0 + 4 * i;
    bf16x8 pk;
#pragma unroll
    for (int j = 0; j < 8; ++j) pk[j] = tile[(dc * 8 + j) * 68 + nr];
    *(bf16x8*)(kvT + obase + (long)(n0 + nr) * NC + d0 + dc * 8) = pk;
  }
}

// ---------------------------------------------------------------------------
// Row softmax with split-K reduction -> P bf16. One wave per row.
// ---------------------------------------------------------------------------
template <int SPLITS>
__global__ __launch_bounds__(256) void softmax_rows(
    const float* __restrict__ attn, __bf16* __restrict__ P) {
  const int row = blockIdx.x * 4 + (threadIdx.x >> 6);
  const int lane = threadIdx.x & 63;
  const long PS = (long)NB * NC * NC;
  const float* src = attn + (long)row * NC;

  float x[8] = {0.f, 0.f, 0.f, 0.f, 0.f, 0.f, 0.f, 0.f};
#pragma unroll
  for (int s = 0; s < SPLITS; ++s) {
    f32x4 v0 = *(const f32x4*)(src + s * PS + lane * 4);
    f32x4 v1 = *(const f32x4*)(src + s * PS + 256 + lane * 4);
#pragma unroll
    for (int r = 0; r < 4; ++r) { x[r] += v0[r]; x[4 + r] += v1[r]; }
  }

  float mx = x[0];
#pragma unroll
  for (int r = 1; r < 8; ++r) mx = fmaxf(mx, x[r]);
#pragma unroll
  for (int off = 32; off >= 1; off >>= 1) mx = fmaxf(mx, __shfl_xor(mx, off));

  float e[8], s = 0.f;
#pragma unroll
  for (int r = 0; r < 8; ++r) { e[r] = __expf(x[r] - mx); s += e[r]; }
#pragma unroll
  for (int off = 32; off >= 1; off >>= 1) s += __shfl_xor(s, off);
  const float inv = 1.0f / s;

  __bf16* dst = P + (long)row * NC;
  bf16x4 h0, h1;
#pragma unroll
  for (int r = 0; r < 4; ++r) {
    h0[r] = (__bf16)(e[r] * inv);
    h1[r] = (__bf16)(e[4 + r] * inv);
  }
  *(bf16x4*)(dst + lane * 4) = h0;
  *(bf16x4*)(dst + 256 + lane * 4) = h1;
}

// ---------------------------------------------------------------------------
extern "C" void kernel_launch(void* const* d_in, const int* in_sizes, int n_in,
                              void* d_out, int out_size, void* d_ws,
                              size_t ws_size, hipStream_t stream) {
  const float* img = (const float*)d_in[0];
  const float* txt = (const float*)d_in[1];
  const float* gamma = (const float*)d_in[2];
  float* out = (float*)d_out;

  const size_t MiB = 1024 * 1024;
  // d_out (128 MiB) scratch until gemm_pv overwrites it:
  //   [0, 64 MiB)   kv16  (bf16)
  //   [68, 100 MiB) attnP (2 splits x 16 MiB f32)
  __bf16* kv16 = (__bf16*)d_out;
  float* attnP = (float*)((char*)d_out + 68 * MiB);
  // ws: [0,64 MiB) kvT, [64,72 MiB) P
  __bf16* kvT = (__bf16*)d_ws;
  __bf16* P = (__bf16*)((char*)d_ws + 64 * MiB);

  // 1) kv prep: bf16 row-major + transposed copies
  prep_kv<<<dim3(NHW / 64, NC / 64, NB), 256, 0, stream>>>(txt, kv16, kvT);

  // 2) attn partials = img(f32) * kv16^T  (512x512, K=4096, split 2)
  gemm_qk<QKSPLIT><<<dim3(4, 4, NB * QKSPLIT), 512, 0, stream>>>(
      img, kv16, attnP);

  // 3) P = softmax(sum of partials)
  softmax_rows<QKSPLIT><<<dim3(NB * NC / 4), 256, 0, stream>>>(attnP, P);

  // 4) out = gamma * (kvT * P^T) + img  (K=512, no-LDS L2-direct fragments)
  gemm_pv<<<dim3(NHW / 64, 4, NB), 256, 0, stream>>>(kvT, P, img, gamma, out);
}

// Round 11
// 227.400 us; speedup vs baseline: 1.4947x; 1.4947x over previous
//
#include <hip/hip_runtime.h>
#include <hip/hip_bf16.h>

// Problem: B=16, C=512, H=W=64 -> HW=4096, fp32.
// attn[b,c,d] = sum_n q[b,c,n]*kv[b,d,n]; P = softmax_d(attn);
// info[b,c,n] = sum_d P[b,c,d]*kv[b,d,n]; out = gamma*info + img.
//
// R11 structure:
//   prep_kv: txt f32 -> kvT bf16 only (kv16 eliminated)
//   gemm_qk: attn partials = img(f32) * txt(f32)^T; BOTH sides f32
//            reg-staged + cvt + swizzled ds_write; dbuf LDS, single
//            barrier per k-step, staggered vmcnt drains; SPLITK=2
//   softmax: partial-sum + row softmax -> P bf16 (ws)
//   gemm_pv: R5-exact (proven 88us plateau): 512 thr, tile 128x128,
//            wave 64x32, single 32 KiB LDS, gload_lds, img in epilogue.

constexpr int NB = 16;
constexpr int NC = 512;
constexpr int NHW = 4096;
constexpr int QKSPLIT = 2;

typedef float f32x4 __attribute__((ext_vector_type(4)));
typedef __bf16 bf16x4 __attribute__((ext_vector_type(4)));
typedef __bf16 bf16x8 __attribute__((ext_vector_type(8)));

__device__ __forceinline__ void gload16(const void* g, void* l) {
  __builtin_amdgcn_global_load_lds(
      (const __attribute__((address_space(1))) void*)g,
      (__attribute__((address_space(3))) void*)l, 16, 0, 0);
}

// ---------------------------------------------------------------------------
// gemm_qk: D[m][n'] = sum_k A[m][k]*B[n'][k]; A = img f32, B = txt f32.
// Tile 128x128, BK=64, 8 waves (2Mx4N), wave tile 64x32.
// Both operands reg-staged f32 -> bf16 cvt -> swizzled ds_write.
// Double-buffered, ONE barrier per k-step, staggered per-wave drains:
//   iter tt: loadA(t+1)[4 vmem] + loadB(t+1)[4 vmem]; compute(cur);
//   vmcnt(4) -> A landed -> writeA(cur^1);
//   vmcnt(0) -> B landed -> writeB(cur^1); lgkmcnt(0); barrier.
// ---------------------------------------------------------------------------
template <int SPLITS>
__global__ __launch_bounds__(512) void gemm_qk(const float* __restrict__ Af,
                                               const float* __restrict__ Bf,
                                               float* __restrict__ Dp) {
  __shared__ __bf16 sA[2][128 * 64];
  __shared__ __bf16 sB[2][128 * 64];

  const int t = threadIdx.x;
  const int lane = t & 63;
  const int wave = t >> 6;
  const int wr = wave >> 2;
  const int wc = wave & 3;

  // XCD-aware remap (NWG % 8 == 0)
  constexpr int NWG = 16 * NB * SPLITS;
  constexpr int QX = NWG / 8;
  int flat = blockIdx.x + 4 * (blockIdx.y + 4 * blockIdx.z);
  flat = (flat & 7) * QX + (flat >> 3);
  const int bx = flat & 3;
  const int by = (flat >> 2) & 3;
  const int bz = flat >> 4;
  const int batch = bz / SPLITS;
  const int split = bz % SPLITS;

  const int aRow0 = bx * 128;
  const int bRow0 = by * 128;
  constexpr int KSUB = NHW / SPLITS;
  constexpr int NT = KSUB / 64;
  const int kBeg = split * KSUB;

  // staging coords (both sides): k-cols c4..c4+3, rows rb + 32*i
  const int c4 = (t & 15) * 4;
  const int rb = t >> 4;
  const float* Abase =
      Af + (long)batch * NC * NHW + (long)(aRow0 + rb) * NHW + kBeg + c4;
  const float* Bbase =
      Bf + (long)batch * NC * NHW + (long)(bRow0 + rb) * NHW + kBeg + c4;

  f32x4 ra[4], rbv[4];
  auto loadA = [&](int kof) {
#pragma unroll
    for (int i = 0; i < 4; ++i)
      ra[i] = *(const f32x4*)(Abase + kof + (long)(32 * i) * NHW);
  };
  auto loadB = [&](int kof) {
#pragma unroll
    for (int i = 0; i < 4; ++i)
      rbv[i] = *(const f32x4*)(Bbase + kof + (long)(32 * i) * NHW);
  };
  auto writeA = [&](int buf) {
#pragma unroll
    for (int i = 0; i < 4; ++i) {
      const int r = rb + 32 * i;
      const int idx = r * 64 + (c4 ^ ((r & 7) << 3));
      bf16x4 h = {(__bf16)ra[i].x, (__bf16)ra[i].y, (__bf16)ra[i].z,
                  (__bf16)ra[i].w};
      *(bf16x4*)&sA[buf][idx] = h;
    }
  };
  auto writeB = [&](int buf) {
#pragma unroll
    for (int i = 0; i < 4; ++i) {
      const int r = rb + 32 * i;
      const int idx = r * 64 + (c4 ^ ((r & 7) << 3));
      bf16x4 h = {(__bf16)rbv[i].x, (__bf16)rbv[i].y, (__bf16)rbv[i].z,
                  (__bf16)rbv[i].w};
      *(bf16x4*)&sB[buf][idx] = h;
    }
  };

  f32x4 acc[4][2] = {};
  auto compute_tile = [&](int buf) {
#pragma unroll
    for (int kk = 0; kk < 2; ++kk) {
      const int kb = kk * 32 + ((lane >> 4) << 3);
      bf16x8 af[4], bfr[2];
#pragma unroll
      for (int m = 0; m < 4; ++m) {
        const int r = wr * 64 + m * 16 + (lane & 15);
        af[m] = *(const bf16x8*)&sA[buf][r * 64 + (kb ^ ((r & 7) << 3))];
      }
#pragma unroll
      for (int n = 0; n < 2; ++n) {
        const int r = wc * 32 + n * 16 + (lane & 15);
        bfr[n] = *(const bf16x8*)&sB[buf][r * 64 + (kb ^ ((r & 7) << 3))];
      }
#pragma unroll
      for (int m = 0; m < 4; ++m)
#pragma unroll
        for (int n = 0; n < 2; ++n)
          acc[m][n] = __builtin_amdgcn_mfma_f32_16x16x32_bf16(
              af[m], bfr[n], acc[m][n], 0, 0, 0);
    }
  };

  // prologue: fully stage tile 0 (A loads first, then B loads)
  loadA(0);  // 4 vmem
  loadB(0);  // 4 vmem
  asm volatile("s_waitcnt vmcnt(4)" ::: "memory");  // A(0) landed
  writeA(0);
  asm volatile("s_waitcnt vmcnt(0)" ::: "memory");  // B(0) landed
  writeB(0);
  asm volatile("s_waitcnt lgkmcnt(0)" ::: "memory");
  __builtin_amdgcn_s_barrier();

  int cur = 0;
#pragma unroll 1
  for (int tt = 0; tt < NT; ++tt) {
    const bool more = (tt + 1) < NT;
    if (more) {
      loadA((tt + 1) * 64);           // 4 vmem -> regs
      loadB((tt + 1) * 64);           // 4 vmem -> regs
      asm volatile("" ::: "memory");  // pin issue point before compute
    }
    compute_tile(cur);  // reads buf cur only; latency cover for loads
    if (more) {
      asm volatile("s_waitcnt vmcnt(4)" ::: "memory");  // A(t+1) landed
      writeA(cur ^ 1);
      asm volatile("s_waitcnt vmcnt(0)" ::: "memory");  // B(t+1) landed
      writeB(cur ^ 1);
      asm volatile("s_waitcnt lgkmcnt(0)" ::: "memory");
      __builtin_amdgcn_s_barrier();  // single barrier: buf cur^1 ready
      cur ^= 1;
    }
  }

  // epilogue: partial store. C/D layout: col=lane&15, row=(lane>>4)*4+reg
  float* D = Dp + ((long)split * NB + batch) * NC * NC;
  const int m0 = aRow0 + wr * 64;
  const int n0 = bRow0 + wc * 32;
#pragma unroll
  for (int m = 0; m < 4; ++m)
#pragma unroll
    for (int n = 0; n < 2; ++n) {
      const int row0 = m0 + m * 16 + ((lane >> 4) << 2);
      const int col = n0 + n * 16 + (lane & 15);
#pragma unroll
      for (int r = 0; r < 4; ++r)
        D[(long)(row0 + r) * NC + col] = acc[m][n][r];
    }
}

// ---------------------------------------------------------------------------
// gemm_pv: out[b][c][sp] = gamma * sum_d kvT[sp][d]*P[c][d] + img[b][c][sp].
// R5-exact proven structure: 512 thr, 8 waves (2x4), tile 128x128, wave
// 64x32, single 32 KiB LDS, gload_lds both sides, img read in epilogue.
// ---------------------------------------------------------------------------
__global__ __launch_bounds__(512) void gemm_pv(const __bf16* __restrict__ A,
                                               const __bf16* __restrict__ B,
                                               const float* __restrict__ img,
                                               const float* __restrict__ gammap,
                                               float* __restrict__ outp) {
  __shared__ __bf16 sA[128 * 64];
  __shared__ __bf16 sB[128 * 64];

  const int t = threadIdx.x;
  const int lane = t & 63;
  const int wave = t >> 6;
  const int wr = wave >> 2;
  const int wc = wave & 3;

  constexpr int GX = NHW / 128;     // 32
  constexpr int NWG = GX * 4 * NB;  // 2048
  constexpr int QX = NWG / 8;
  int flat = blockIdx.x + GX * (blockIdx.y + 4 * blockIdx.z);
  flat = (flat & 7) * QX + (flat >> 3);
  const int bx = flat % GX;
  const int by = (flat / GX) & 3;
  const int batch = flat / (GX * 4);

  const int aRow0 = bx * 128;
  const int bRow0 = by * 128;

  const int rl = lane >> 3;
  const int csrc = ((lane & 7) ^ rl) * 8;
  const __bf16* Abase =
      A + (long)batch * NHW * NC + (long)(aRow0 + wave * 16 + rl) * NC + csrc;
  const __bf16* Bbase =
      B + (long)batch * NC * NC + (long)(bRow0 + wave * 16 + rl) * NC + csrc;
  const int ldsOff = wave * 16 * 64;

  f32x4 acc[4][2] = {};

#pragma unroll 1
  for (int k0 = 0; k0 < NC; k0 += 64) {
#pragma unroll
    for (int i = 0; i < 2; ++i) {
      gload16(Abase + k0 + (long)(i * 8) * NC, &sA[ldsOff + i * 8 * 64]);
      gload16(Bbase + k0 + (long)(i * 8) * NC, &sB[ldsOff + i * 8 * 64]);
    }
    __syncthreads();  // compiler drains vmcnt before barrier (m97 structure)
#pragma unroll
    for (int kk = 0; kk < 2; ++kk) {
      const int kb = kk * 32 + ((lane >> 4) << 3);
      bf16x8 af[4], bfr[2];
#pragma unroll
      for (int m = 0; m < 4; ++m) {
        const int r = wr * 64 + m * 16 + (lane & 15);
        af[m] = *(const bf16x8*)&sA[r * 64 + (kb ^ ((r & 7) << 3))];
      }
#pragma unroll
      for (int n = 0; n < 2; ++n) {
        const int r = wc * 32 + n * 16 + (lane & 15);
        bfr[n] = *(const bf16x8*)&sB[r * 64 + (kb ^ ((r & 7) << 3))];
      }
#pragma unroll
      for (int m = 0; m < 4; ++m)
#pragma unroll
        for (int n = 0; n < 2; ++n)
          acc[m][n] = __builtin_amdgcn_mfma_f32_16x16x32_bf16(
              af[m], bfr[n], acc[m][n], 0, 0, 0);
    }
    __syncthreads();
  }

  // epilogue: out[b][ch][sp] = gamma*acc + img
  const float g = gammap[0];
  const long obase = (long)batch * NC * NHW;
  const int sp0 = aRow0 + wr * 64;
  const int ch0 = bRow0 + wc * 32;
#pragma unroll
  for (int m = 0; m < 4; ++m)
#pragma unroll
    for (int n = 0; n < 2; ++n) {
      const int sp = sp0 + m * 16 + ((lane >> 4) << 2);
      const int ch = ch0 + n * 16 + (lane & 15);
      const long idx = obase + (long)ch * NHW + sp;
      f32x4 iv = *(const f32x4*)(img + idx);
      f32x4 ov;
#pragma unroll
      for (int r = 0; r < 4; ++r) ov[r] = g * acc[m][n][r] + iv[r];
      *(f32x4*)(outp + idx) = ov;
    }
}

// ---------------------------------------------------------------------------
// prep_kv: kv[b][d][n] f32 -> kvT[b][n][d] bf16 (transpose only; kv16 gone).
// ---------------------------------------------------------------------------
__global__ __launch_bounds__(256) void prep_kv(const float* __restrict__ kv,
                                               __bf16* __restrict__ kvT) {
  __shared__ __bf16 tile[64 * 68];
  const int t = threadIdx.x;
  const int n0 = blockIdx.x * 64;
  const int d0 = blockIdx.y * 64;
  const long ibase = (long)blockIdx.z * NC * NHW;

  const int nc4 = (t & 15) * 4;
  const int dr0 = t >> 4;
#pragma unroll
  for (int i = 0; i < 4; ++i) {
    const int dr = dr0 + 16 * i;
    f32x4 v = *(const f32x4*)(kv + ibase + (long)(d0 + dr) * NHW + n0 + nc4);
    bf16x4 h = {(__bf16)v.x, (__bf16)v.y, (__bf16)v.z, (__bf16)v.w};
    *(bf16x4*)&tile[dr * 68 + nc4] = h;
  }
  __syncthreads();

  const long obase = (long)blockIdx.z * NHW * NC;
  const int nr = t >> 2;
  const int dc0 = t & 3;
#pragma unroll
  for (int i = 0; i < 2; ++i) {
    const int dc = dc0 + 4 * i;
    bf16x8 pk;
#pragma unroll
    for (int j = 0; j < 8; ++j) pk[j] = tile[(dc * 8 + j) * 68 + nr];
    *(bf16x8*)(kvT + obase + (long)(n0 + nr) * NC + d0 + dc * 8) = pk;
  }
}

// ---------------------------------------------------------------------------
// Row softmax with split-K reduction -> P bf16. One wave per row.
// ---------------------------------------------------------------------------
template <int SPLITS>
__global__ __launch_bounds__(256) void softmax_rows(
    const float* __restrict__ attn, __bf16* __restrict__ P) {
  const int row = blockIdx.x * 4 + (threadIdx.x >> 6);
  const int lane = threadIdx.x & 63;
  const long PS = (long)NB * NC * NC;
  const float* src = attn + (long)row * NC;

  float x[8] = {0.f, 0.f, 0.f, 0.f, 0.f, 0.f, 0.f, 0.f};
#pragma unroll
  for (int s = 0; s < SPLITS; ++s) {
    f32x4 v0 = *(const f32x4*)(src + s * PS + lane * 4);
    f32x4 v1 = *(const f32x4*)(src + s * PS + 256 + lane * 4);
#pragma unroll
    for (int r = 0; r < 4; ++r) { x[r] += v0[r]; x[4 + r] += v1[r]; }
  }

  float mx = x[0];
#pragma unroll
  for (int r = 1; r < 8; ++r) mx = fmaxf(mx, x[r]);
#pragma unroll
  for (int off = 32; off >= 1; off >>= 1) mx = fmaxf(mx, __shfl_xor(mx, off));

  float e[8], s = 0.f;
#pragma unroll
  for (int r = 0; r < 8; ++r) { e[r] = __expf(x[r] - mx); s += e[r]; }
#pragma unroll
  for (int off = 32; off >= 1; off >>= 1) s += __shfl_xor(s, off);
  const float inv = 1.0f / s;

  __bf16* dst = P + (long)row * NC;
  bf16x4 h0, h1;
#pragma unroll
  for (int r = 0; r < 4; ++r) {
    h0[r] = (__bf16)(e[r] * inv);
    h1[r] = (__bf16)(e[4 + r] * inv);
  }
  *(bf16x4*)(dst + lane * 4) = h0;
  *(bf16x4*)(dst + 256 + lane * 4) = h1;
}

// ---------------------------------------------------------------------------
extern "C" void kernel_launch(void* const* d_in, const int* in_sizes, int n_in,
                              void* d_out, int out_size, void* d_ws,
                              size_t ws_size, hipStream_t stream) {
  const float* img = (const float*)d_in[0];
  const float* txt = (const float*)d_in[1];
  const float* gamma = (const float*)d_in[2];
  float* out = (float*)d_out;

  const size_t MiB = 1024 * 1024;
  // d_out (128 MiB) scratch until gemm_pv overwrites it:
  //   [0, 34 MiB) attnP (2 splits x 16.8 MiB f32) — consumed by softmax
  //   before gemm_pv writes out.
  float* attnP = (float*)d_out;
  // ws: [0,64 MiB) kvT, [64,72 MiB) P
  __bf16* kvT = (__bf16*)d_ws;
  __bf16* P = (__bf16*)((char*)d_ws + 64 * MiB);

  // 1) kv prep: transposed bf16 copy only
  prep_kv<<<dim3(NHW / 64, NC / 64, NB), 256, 0, stream>>>(txt, kvT);

  // 2) attn partials = img(f32) * txt(f32)^T  (512x512, K=4096, split 2)
  gemm_qk<QKSPLIT><<<dim3(4, 4, NB * QKSPLIT), 512, 0, stream>>>(
      img, txt, attnP);

  // 3) P = softmax(sum of partials)
  softmax_rows<QKSPLIT><<<dim3(NB * NC / 4), 256, 0, stream>>>(attnP, P);

  // 4) out = gamma * (kvT * P^T) + img  (K=512, R5-exact structure)
  gemm_pv<<<dim3(NHW / 128, 4, NB), 512, 0, stream>>>(kvT, P, img, gamma, out);
}

// Round 12
// 222.706 us; speedup vs baseline: 1.5262x; 1.0211x over previous
//
#include <hip/hip_runtime.h>
#include <hip/hip_bf16.h>

// Problem: B=16, C=512, H=W=64 -> HW=4096, fp32.
// attn[b,c,d] = sum_n q[b,c,n]*kv[b,d,n]; P = softmax_d(attn);
// info[b,c,n] = sum_d P[b,c,d]*kv[b,d,n]; out = gamma*info + img.
//
// R12 = R5-exact (measured best, 216 us) + pv L2-aware tile order:
//   prep_kv: txt f32 -> kv16 bf16 (d_out) + kvT bf16 (ws)     [~45 us, at BW floor]
//   gemm_qk: attn partials = img(f32 reg-staged) * kv16^T(gload_lds),
//            dbuf LDS, early-issue, SPLITK=2                   [~70 us]
//   softmax: partial-sum + row softmax -> P bf16               [~13 us]
//   gemm_pv: out = gamma*(kvT*P^T)+img, m97 single-buffer      [88 -> ~78 us?]
//            NEW: by (channel-block) varies FASTEST in the XCD chunk so the
//            4 column-tiles reuse one 128-row kvT slab (~1 MB active window
//            vs 4.2 MB/batch sweep x4) -> kvT HBM re-fetch eliminated.

constexpr int NB = 16;
constexpr int NC = 512;
constexpr int NHW = 4096;
constexpr int QKSPLIT = 2;

typedef float f32x4 __attribute__((ext_vector_type(4)));
typedef __bf16 bf16x4 __attribute__((ext_vector_type(4)));
typedef __bf16 bf16x8 __attribute__((ext_vector_type(8)));

__device__ __forceinline__ void gload16(const void* g, void* l) {
  __builtin_amdgcn_global_load_lds(
      (const __attribute__((address_space(1))) void*)g,
      (__attribute__((address_space(3))) void*)l, 16, 0, 0);
}

// ---------------------------------------------------------------------------
// gemm_qk (R5-exact): D[m][n'] = sum_k A[m][k]*B[n'][k]; A img f32, B kv16.
// Tile 128x128, BK=64, 8 waves (2Mx4N), wave tile 64x32. A reg-staged
// f32->cvt->swizzled ds_write; B gload_lds (source-XOR). Dbuf, early-issue.
// ---------------------------------------------------------------------------
template <int SPLITS>
__global__ __launch_bounds__(512) void gemm_qk(const float* __restrict__ Af,
                                               const __bf16* __restrict__ B,
                                               float* __restrict__ Dp) {
  __shared__ __bf16 sA[2][128 * 64];
  __shared__ __bf16 sB[2][128 * 64];

  const int t = threadIdx.x;
  const int lane = t & 63;
  const int wave = t >> 6;
  const int wr = wave >> 2;
  const int wc = wave & 3;

  constexpr int NWG = 16 * NB * SPLITS;
  constexpr int QX = NWG / 8;
  int flat = blockIdx.x + 4 * (blockIdx.y + 4 * blockIdx.z);
  flat = (flat & 7) * QX + (flat >> 3);
  const int bx = flat & 3;
  const int by = (flat >> 2) & 3;
  const int bz = flat >> 4;
  const int batch = bz / SPLITS;
  const int split = bz % SPLITS;

  const int aRow0 = bx * 128;
  const int bRow0 = by * 128;
  constexpr int KSUB = NHW / SPLITS;
  constexpr int NT = KSUB / 64;
  const int kBeg = split * KSUB;

  const int rl = lane >> 3;
  const int csrc = ((lane & 7) ^ rl) * 8;
  const __bf16* Bbase = B + (long)batch * NC * NHW +
                        (long)(bRow0 + wave * 16 + rl) * NHW + csrc + kBeg;
  const int ldsOff = wave * 16 * 64;

  const int c4 = (t & 15) * 4;
  const int rb = t >> 4;
  const float* Abase =
      Af + (long)batch * NC * NHW + (long)(aRow0 + rb) * NHW + kBeg + c4;

  f32x4 ra[4];
  auto loadA = [&](int kof) {
#pragma unroll
    for (int i = 0; i < 4; ++i)
      ra[i] = *(const f32x4*)(Abase + kof + (long)(32 * i) * NHW);
  };
  auto writeA = [&](int buf) {
#pragma unroll
    for (int i = 0; i < 4; ++i) {
      const int r = rb + 32 * i;
      const int idx = r * 64 + (c4 ^ ((r & 7) << 3));
      bf16x4 h = {(__bf16)ra[i].x, (__bf16)ra[i].y, (__bf16)ra[i].z,
                  (__bf16)ra[i].w};
      *(bf16x4*)&sA[buf][idx] = h;
    }
  };
  auto stageB = [&](int buf, int kof) {
#pragma unroll
    for (int i = 0; i < 2; ++i)
      gload16(Bbase + kof + (long)(i * 8) * NHW, &sB[buf][ldsOff + i * 8 * 64]);
  };

  f32x4 acc[4][2] = {};
  auto compute_tile = [&](int buf) {
#pragma unroll
    for (int kk = 0; kk < 2; ++kk) {
      const int kb = kk * 32 + ((lane >> 4) << 3);
      bf16x8 af[4], bfr[2];
#pragma unroll
      for (int m = 0; m < 4; ++m) {
        const int r = wr * 64 + m * 16 + (lane & 15);
        af[m] = *(const bf16x8*)&sA[buf][r * 64 + (kb ^ ((r & 7) << 3))];
      }
#pragma unroll
      for (int n = 0; n < 2; ++n) {
        const int r = wc * 32 + n * 16 + (lane & 15);
        bfr[n] = *(const bf16x8*)&sB[buf][r * 64 + (kb ^ ((r & 7) << 3))];
      }
#pragma unroll
      for (int m = 0; m < 4; ++m)
#pragma unroll
        for (int n = 0; n < 2; ++n)
          acc[m][n] = __builtin_amdgcn_mfma_f32_16x16x32_bf16(
              af[m], bfr[n], acc[m][n], 0, 0, 0);
    }
  };

  // prologue: fully stage tile 0
  stageB(0, 0);
  loadA(0);
  asm volatile("s_waitcnt vmcnt(0)" ::: "memory");
  writeA(0);
  __syncthreads();

  int cur = 0;
#pragma unroll 1
  for (int tt = 0; tt < NT; ++tt) {
    const bool more = (tt + 1) < NT;
    if (more) {
      stageB(cur ^ 1, (tt + 1) * 64);  // async into other buffer
      loadA((tt + 1) * 64);            // f32 -> regs, hides under MFMA
      asm volatile("" ::: "memory");   // pin issue point
    }
    compute_tile(cur);
    if (more) {
      __builtin_amdgcn_s_barrier();  // all waves done reading buf[cur]
      asm volatile("s_waitcnt vmcnt(0)" ::: "memory");  // ra + B landed
      writeA(cur ^ 1);
      asm volatile("s_waitcnt lgkmcnt(0)" ::: "memory");
      __builtin_amdgcn_s_barrier();  // buf[cur^1] fully staged
      cur ^= 1;
    }
  }

  // epilogue: partial store. C/D layout: col=lane&15, row=(lane>>4)*4+reg
  float* D = Dp + ((long)split * NB + batch) * NC * NC;
  const int m0 = aRow0 + wr * 64;
  const int n0 = bRow0 + wc * 32;
#pragma unroll
  for (int m = 0; m < 4; ++m)
#pragma unroll
    for (int n = 0; n < 2; ++n) {
      const int row0 = m0 + m * 16 + ((lane >> 4) << 2);
      const int col = n0 + n * 16 + (lane & 15);
#pragma unroll
      for (int r = 0; r < 4; ++r)
        D[(long)(row0 + r) * NC + col] = acc[m][n][r];
    }
}

// ---------------------------------------------------------------------------
// gemm_pv (R5 structure + by-fastest L2 order): out = gamma*(kvT*P^T)+img.
// 512 thr, 8 waves (2x4), tile 128x128, wave 64x32, single 32 KiB LDS,
// gload_lds both sides, img read in epilogue.
// Tile order: within each XCD's contiguous newflat chunk, by (channel block)
// varies fastest -> 4 column-tiles share one kvT row-slab (L2-resident).
// ---------------------------------------------------------------------------
__global__ __launch_bounds__(512) void gemm_pv(const __bf16* __restrict__ A,
                                               const __bf16* __restrict__ B,
                                               const float* __restrict__ img,
                                               const float* __restrict__ gammap,
                                               float* __restrict__ outp) {
  __shared__ __bf16 sA[128 * 64];
  __shared__ __bf16 sB[128 * 64];

  const int t = threadIdx.x;
  const int lane = t & 63;
  const int wave = t >> 6;
  const int wr = wave >> 2;
  const int wc = wave & 3;

  constexpr int GX = NHW / 128;     // 32
  constexpr int NWG = GX * 4 * NB;  // 2048
  constexpr int QX = NWG / 8;       // 256
  int flat = blockIdx.x + GX * (blockIdx.y + 4 * blockIdx.z);
  flat = (flat & 7) * QX + (flat >> 3);
  // NEW decomposition: by fastest, then bx, then batch.
  const int by = flat & 3;
  const int bx = (flat >> 2) & 31;
  const int batch = flat >> 7;

  const int aRow0 = bx * 128;
  const int bRow0 = by * 128;

  const int rl = lane >> 3;
  const int csrc = ((lane & 7) ^ rl) * 8;
  const __bf16* Abase =
      A + (long)batch * NHW * NC + (long)(aRow0 + wave * 16 + rl) * NC + csrc;
  const __bf16* Bbase =
      B + (long)batch * NC * NC + (long)(bRow0 + wave * 16 + rl) * NC + csrc;
  const int ldsOff = wave * 16 * 64;

  f32x4 acc[4][2] = {};

#pragma unroll 1
  for (int k0 = 0; k0 < NC; k0 += 64) {
#pragma unroll
    for (int i = 0; i < 2; ++i) {
      gload16(Abase + k0 + (long)(i * 8) * NC, &sA[ldsOff + i * 8 * 64]);
      gload16(Bbase + k0 + (long)(i * 8) * NC, &sB[ldsOff + i * 8 * 64]);
    }
    __syncthreads();  // drains vmcnt before barrier (m97 structure)
#pragma unroll
    for (int kk = 0; kk < 2; ++kk) {
      const int kb = kk * 32 + ((lane >> 4) << 3);
      bf16x8 af[4], bfr[2];
#pragma unroll
      for (int m = 0; m < 4; ++m) {
        const int r = wr * 64 + m * 16 + (lane & 15);
        af[m] = *(const bf16x8*)&sA[r * 64 + (kb ^ ((r & 7) << 3))];
      }
#pragma unroll
      for (int n = 0; n < 2; ++n) {
        const int r = wc * 32 + n * 16 + (lane & 15);
        bfr[n] = *(const bf16x8*)&sB[r * 64 + (kb ^ ((r & 7) << 3))];
      }
#pragma unroll
      for (int m = 0; m < 4; ++m)
#pragma unroll
        for (int n = 0; n < 2; ++n)
          acc[m][n] = __builtin_amdgcn_mfma_f32_16x16x32_bf16(
              af[m], bfr[n], acc[m][n], 0, 0, 0);
    }
    __syncthreads();
  }

  // epilogue: out[b][ch][sp] = gamma*acc + img
  const float g = gammap[0];
  const long obase = (long)batch * NC * NHW;
  const int sp0 = aRow0 + wr * 64;
  const int ch0 = bRow0 + wc * 32;
#pragma unroll
  for (int m = 0; m < 4; ++m)
#pragma unroll
    for (int n = 0; n < 2; ++n) {
      const int sp = sp0 + m * 16 + ((lane >> 4) << 2);
      const int ch = ch0 + n * 16 + (lane & 15);
      const long idx = obase + (long)ch * NHW + sp;
      f32x4 iv = *(const f32x4*)(img + idx);
      f32x4 ov;
#pragma unroll
      for (int r = 0; r < 4; ++r) ov[r] = g * acc[m][n][r] + iv[r];
      *(f32x4*)(outp + idx) = ov;
    }
}

// ---------------------------------------------------------------------------
// prep_kv: kv[b][d][n] f32 -> kv16[b][d][n] bf16 AND kvT[b][n][d] bf16.
// ---------------------------------------------------------------------------
__global__ __launch_bounds__(256) void prep_kv(const float* __restrict__ kv,
                                               __bf16* __restrict__ kv16,
                                               __bf16* __restrict__ kvT) {
  __shared__ __bf16 tile[64 * 68];
  const int t = threadIdx.x;
  const int n0 = blockIdx.x * 64;
  const int d0 = blockIdx.y * 64;
  const long ibase = (long)blockIdx.z * NC * NHW;

  const int nc4 = (t & 15) * 4;
  const int dr0 = t >> 4;
#pragma unroll
  for (int i = 0; i < 4; ++i) {
    const int dr = dr0 + 16 * i;
    f32x4 v = *(const f32x4*)(kv + ibase + (long)(d0 + dr) * NHW + n0 + nc4);
    bf16x4 h = {(__bf16)v.x, (__bf16)v.y, (__bf16)v.z, (__bf16)v.w};
    *(bf16x4*)&tile[dr * 68 + nc4] = h;
    *(bf16x4*)(kv16 + ibase + (long)(d0 + dr) * NHW + n0 + nc4) = h;
  }
  __syncthreads();

  const long obase = (long)blockIdx.z * NHW * NC;
  const int nr = t >> 2;
  const int dc0 = t & 3;
#pragma unroll
  for (int i = 0; i < 2; ++i) {
    const int dc = dc0 + 4 * i;
    bf16x8 pk;
#pragma unroll
    for (int j = 0; j < 8; ++j) pk[j] = tile[(dc * 8 + j) * 68 + nr];
    *(bf16x8*)(kvT + obase + (long)(n0 + nr) * NC + d0 + dc * 8) = pk;
  }
}

// ---------------------------------------------------------------------------
// Row softmax with split-K reduction -> P bf16. One wave per row.
// ---------------------------------------------------------------------------
template <int SPLITS>
__global__ __launch_bounds__(256) void softmax_rows(
    const float* __restrict__ attn, __bf16* __restrict__ P) {
  const int row = blockIdx.x * 4 + (threadIdx.x >> 6);
  const int lane = threadIdx.x & 63;
  const long PS = (long)NB * NC * NC;
  const float* src = attn + (long)row * NC;

  float x[8] = {0.f, 0.f, 0.f, 0.f, 0.f, 0.f, 0.f, 0.f};
#pragma unroll
  for (int s = 0; s < SPLITS; ++s) {
    f32x4 v0 = *(const f32x4*)(src + s * PS + lane * 4);
    f32x4 v1 = *(const f32x4*)(src + s * PS + 256 + lane * 4);
#pragma unroll
    for (int r = 0; r < 4; ++r) { x[r] += v0[r]; x[4 + r] += v1[r]; }
  }

  float mx = x[0];
#pragma unroll
  for (int r = 1; r < 8; ++r) mx = fmaxf(mx, x[r]);
#pragma unroll
  for (int off = 32; off >= 1; off >>= 1) mx = fmaxf(mx, __shfl_xor(mx, off));

  float e[8], s = 0.f;
#pragma unroll
  for (int r = 0; r < 8; ++r) { e[r] = __expf(x[r] - mx); s += e[r]; }
#pragma unroll
  for (int off = 32; off >= 1; off >>= 1) s += __shfl_xor(s, off);
  const float inv = 1.0f / s;

  __bf16* dst = P + (long)row * NC;
  bf16x4 h0, h1;
#pragma unroll
  for (int r = 0; r < 4; ++r) {
    h0[r] = (__bf16)(e[r] * inv);
    h1[r] = (__bf16)(e[4 + r] * inv);
  }
  *(bf16x4*)(dst + lane * 4) = h0;
  *(bf16x4*)(dst + 256 + lane * 4) = h1;
}

// ---------------------------------------------------------------------------
extern "C" void kernel_launch(void* const* d_in, const int* in_sizes, int n_in,
                              void* d_out, int out_size, void* d_ws,
                              size_t ws_size, hipStream_t stream) {
  const float* img = (const float*)d_in[0];
  const float* txt = (const float*)d_in[1];
  const float* gamma = (const float*)d_in[2];
  float* out = (float*)d_out;

  const size_t MiB = 1024 * 1024;
  // d_out (128 MiB) scratch until gemm_pv overwrites it:
  //   [0, 64 MiB)   kv16  (bf16)
  //   [68, 100 MiB) attnP (2 splits x 16 MiB f32)
  __bf16* kv16 = (__bf16*)d_out;
  float* attnP = (float*)((char*)d_out + 68 * MiB);
  // ws: [0,64 MiB) kvT, [64,72 MiB) P
  __bf16* kvT = (__bf16*)d_ws;
  __bf16* P = (__bf16*)((char*)d_ws + 64 * MiB);

  // 1) kv prep: bf16 row-major + transposed copies
  prep_kv<<<dim3(NHW / 64, NC / 64, NB), 256, 0, stream>>>(txt, kv16, kvT);

  // 2) attn partials = img(f32) * kv16^T  (512x512, K=4096, split 2)
  gemm_qk<QKSPLIT><<<dim3(4, 4, NB * QKSPLIT), 512, 0, stream>>>(
      img, kv16, attnP);

  // 3) P = softmax(sum of partials)
  softmax_rows<QKSPLIT><<<dim3(NB * NC / 4), 256, 0, stream>>>(attnP, P);

  // 4) out = gamma * (kvT * P^T) + img  (K=512, by-fastest L2 order)
  gemm_pv<<<dim3(NHW / 128, 4, NB), 512, 0, stream>>>(kvT, P, img, gamma, out);
}